// Round 15
// baseline (167.737 us; speedup 1.0000x reference)
//
#include <hip/hip_runtime.h>
#include <math.h>

#define BB 4
#define LL 512000
#define NF 512
#define TT 3997
#define FF 257
#define TWO_PI 6.28318530717958647692f
#define PI_F 3.14159265358979323846f
// fl32(2*pi) — what the f32 numpy port uses building theta and window args:
#define TPI_F32 6.28318548202514648f

static const size_t SPEC_N = (size_t)BB * FF * TT;   // 4,108,916
static const size_t BNT    = (size_t)BB * NF * TT;   // 8,185,856
// layout B (confirmed r11): spec | stft real-part (BNT) | real | imag | phase

#define AB_IM  3.0e-5f
#define RE_MAX 1.0e-4f
#define Z2_MIN 1.0e-8f

__device__ __forceinline__ float neg_zero() { return __uint_as_float(0x80000000u); }

// Barriered ops: exactly one IEEE-RN rounding each (stops -ffp-contract=fast
// from fusing where numpy has separate ops).
__device__ __forceinline__ float mulrn(float a, float b) { float t = a * b; asm("" : "+v"(t)); return t; }
__device__ __forceinline__ float addrn(float a, float b) { float t = a + b; asm("" : "+v"(t)); return t; }
// Single-rounded fused a*b+c (npyv_muladd on AVX512 = FMA):
__device__ __forceinline__ float fmarn(float a, float b, float c) { float t = fmaf(a, b, c); asm("" : "+v"(t)); return t; }

// np f32 theta: fl32(fl32(2pi)*k)/512  (k = f*n < 2^24 exact; /512 exact)
__device__ __forceinline__ float theta32(int k) {
    return mulrn(TPI_F32, (float)k) / 512.0f;
}

__device__ __forceinline__ int bitrev6(int l) { return (int)(__brev((unsigned)l) >> 26); }

// Wave-private LDS sync (rule #18: sched_barrier after inline-asm waitcnt)
#define WAVE_SYNC() do { asm volatile("s_waitcnt lgkmcnt(0)" ::: "memory"); \
                         __builtin_amdgcn_sched_barrier(0); } while (0)

// _mm512_reduce_add_ps tree over 16 partials held by lanes base..base+15
__device__ __forceinline__ float hsum16(float s, int base) {
    float q[4];
#pragma unroll
    for (int k = 0; k < 4; ++k) {
        float a = addrn(__shfl(s, base + k),     __shfl(s, base + k + 8));
        float b = addrn(__shfl(s, base + k + 4), __shfl(s, base + k + 12));
        q[k] = addrn(a, b);
    }
    return addrn(addrn(q[0], q[2]), addrn(q[1], q[3]));
}

// ---------------------------------------------------------------------------
// Setup: s256f[n] = fl32(sin_f64(theta32(256n))) — f32-theta sin basis row.
__global__ void dstft_sin256(float* __restrict__ s256g)
{
    int n = threadIdx.x;   // 512 threads
    s256g[n] = (float)sin((double)theta32(256 * n));
}

// ---------------------------------------------------------------------------
// Shared body: register FFT (8x64 Cooley-Tukey, shfl-based) + gold recompute
// for flagged frames. Results in vout[8]: bin f = j + 8*bitrev6(lane).
__device__ __forceinline__ void dstft_frame_compute(
    const float* __restrict__ x,
    float strd, float wl, float wpow,
    float2* vout, float* exrow, const float* s256f,
    int lane, int t, int b, bool active, float* nyq_out)
{
    double strd64  = fmin(fmax((double)strd, 0.0), 512.0);
    double frame64 = strd64 * (double)t;
    double frac64  = frame64 - floor(frame64);
    int    i0      = (int)floor(frame64);
    float  frac    = (float)frac64;

    // ---- fast window (cosf) + wave-parallel psum
    float shift = (wl - 511.0f) * 0.5f;
    float lower = floorf((511.0f - wl) * 0.5f);
    float upper = ceilf ((511.0f + wl) * 0.5f);

    float wv_[8];
    float psum = 0.0f;
#pragma unroll
    for (int j = 0; j < 8; ++j) {
        int n = lane + 64 * j;
        float base = (float)n - frac;
        float w = 0.0f;
        if (base > lower && base < upper)
            w = 0.5f - 0.5f * cosf(TWO_PI * (base + shift) / wl);
        wv_[j] = w;
        psum += w;
    }
#pragma unroll
    for (int off = 32; off > 0; off >>= 1) psum += __shfl_xor(psum, off);
    float inv = 1.0f / psum;

    const bool dopow = (wpow != 1.0f);
    float xraw[8], tap[8];
#pragma unroll
    for (int j = 0; j < 8; ++j) {
        int n   = lane + 64 * j;
        int idx = i0 + n;
        float xv = (active && idx >= 0 && idx < LL) ? x[(size_t)b * LL + idx] : 0.0f;
        xraw[j] = xv;
        float ww = wv_[j] * inv;
        if (dopow) ww = powf(ww, wpow);
        tap[j] = xv * ww;
        exrow[n] = tap[j];           // staged for npyv dots (conflict-free)
    }

    // ---- step 1: 8-point real-input DFT over slots (n2 = j)
    {
        const float Cq = 0.70710678118654752440f;
        float u0 = tap[0] + tap[4], u1 = tap[0] - tap[4];
        float u2 = tap[2] + tap[6], u3 = tap[2] - tap[6];
        float u4 = tap[1] + tap[5], u5 = tap[1] - tap[5];
        float u6 = tap[3] + tap[7], u7 = tap[3] - tap[7];
        float a0 = u0 + u2, a2 = u0 - u2;
        float b0 = u4 + u6, b2 = u4 - u6;
        float d1 = Cq * (u5 - u7), d2 = Cq * (u5 + u7);
        vout[0] = make_float2(a0 + b0, 0.0f);
        vout[4] = make_float2(a0 - b0, 0.0f);
        vout[1] = make_float2(u1 + d1, -(u3 + d2));
        vout[7] = make_float2(u1 + d1,  (u3 + d2));
        vout[5] = make_float2(u1 - d1, -(u3 - d2));
        vout[3] = make_float2(u1 - d1,  (u3 - d2));
        vout[2] = make_float2(a2, -b2);
        vout[6] = make_float2(a2,  b2);
    }
    // ---- step 2: twiddle by W512^{lane*k2} (base power chain)
    {
        float bs, bc;
        sincosf(-(TWO_PI / 512.0f) * (float)lane, &bs, &bc);
        float wc = bc, ws = bs;
#pragma unroll
        for (int k2 = 1; k2 < 8; ++k2) {
            float vx = vout[k2].x, vy = vout[k2].y;
            vout[k2] = make_float2(vx * wc - vy * ws, vx * ws + vy * wc);
            if (k2 < 7) {
                float nc = wc * bc - ws * bs;
                float ns = wc * bs + ws * bc;
                wc = nc; ws = ns;
            }
        }
    }
    // ---- step 3: 64-pt DIF across lanes, 6 stages (masks 32..1)
#pragma unroll
    for (int st = 0; st < 6; ++st) {
        int h = 32 >> st;
        int pos = lane & (h - 1);
        bool hi = (lane & h) != 0;
        float ss, sc;
        sincosf(-PI_F * (float)pos / (float)h, &ss, &sc);
#pragma unroll
        for (int j = 0; j < 8; ++j) {
            float px = __shfl_xor(vout[j].x, h);
            float py = __shfl_xor(vout[j].y, h);
            if (hi) {
                float rx = px - vout[j].x, ry = py - vout[j].y;
                vout[j] = make_float2(rx * sc - ry * ss, rx * ss + ry * sc);
            } else {
                vout[j] = make_float2(vout[j].x + px, vout[j].y + py);
            }
        }
    }
    WAVE_SYNC();   // exrow tap writes landed

    // imag[256] = -(npyv forward dot of taps with s256f) — always
    {
        float s = 0.0f;
        if (lane < 16) {
#pragma unroll 1
            for (int i = 0; i < 8; ++i) {
                int base = 64 * i + lane;
                s = fmarn(exrow[base +  0], s256f[base +  0], s);
                s = fmarn(exrow[base + 16], s256f[base + 16], s);
                s = fmarn(exrow[base + 32], s256f[base + 32], s);
                s = fmarn(exrow[base + 48], s256f[base + 48], s);
            }
        }
        *nyq_out = -hsum16(s, 0);
    }

    // ---- flag scan: f = j + 8*bitrev6(lane). Phase bins only (f<=256).
    // j==0: lane0 -> f=0, lane1 -> f=256 (quadrant risk, |re| tiny).
    // even lanes -> f in 1..255: branch-cut risk. Odd lanes (f>=257): never.
    unsigned long long flags[8];
    unsigned long long anyf = 0ULL;
#pragma unroll
    for (int j = 0; j < 8; ++j) {
        float2 vv = vout[j];
        bool flg = false;
        if (active) {
            if (j == 0 && (lane == 0 || lane == 1)) {
                flg = fabsf(vv.x) < RE_MAX;
            } else if ((lane & 1) == 0) {
                flg = (fabsf(vv.y) < AB_IM && vv.x < RE_MAX) ||
                      (vv.x * vv.x + vv.y * vv.y < Z2_MIN);
            }
        }
        flags[j] = __ballot(flg);
        anyf |= flags[j];
    }

    if (anyf) {
        // ---- gold window (f32 ops, f64-rounded cos) — R13-verified sequence
        float g_shift = mulrn(addrn(wl - 512.0f, 1.0f), 0.5f);
        float g_lower = floorf(mulrn(511.0f - wl, 0.5f));
        float g_upper = ceilf (mulrn(511.0f + wl, 0.5f));
        float gw[8];
#pragma unroll
        for (int j = 0; j < 8; ++j) {
            int n = lane + 64 * j;
            float base = (float)n - frac;
            float w = 0.0f;
            if (base > g_lower && base < g_upper) {
                float arg = mulrn(TPI_F32, addrn(base, g_shift)) / wl;
                w = 0.5f - mulrn(0.5f, (float)cos((double)arg));
            }
            gw[j] = w;
            exrow[n] = w;
        }
        WAVE_SYNC();
        // psum: np.sum(axis=0) = strictly sequential over n
        float ps = 0.0f;
        if (lane == 0) {
#pragma unroll 1
            for (int n = 0; n < NF; ++n) ps = addrn(ps, exrow[n]);
        }
        ps = __shfl(ps, 0);
#pragma unroll
        for (int j = 0; j < 8; ++j) {
            int n = lane + 64 * j;
            float ww = gw[j] / ps;                 // np: tap / sum (f32 div)
            if (dopow) ww = powf(ww, wpow);
            exrow[n] = mulrn(xraw[j], ww);         // gold tapered
        }
        WAVE_SYNC();

#pragma unroll
        for (int j = 0; j < 8; ++j) {
            unsigned long long m = flags[j];
            while (m) {
                int src = (int)(__ffsll(m) - 1);
                m &= m - 1;
                int ff = j + 8 * bitrev6(src);
                // lanes 0-15: sin partials; 16-31: cos partials; FORWARD chain
                float s = 0.0f;
                if (lane < 32) {
                    int L = lane & 15;
                    bool isCos = lane >= 16;
#pragma unroll 1
                    for (int i = 0; i < 8; ++i) {
                        int base = 64 * i + L;
#pragma unroll
                        for (int B = 0; B < 4; ++B) {
                            int n = base + 16 * B;
                            double sv, cv;
                            sincos((double)theta32(ff * n), &sv, &cv);
                            s = fmarn(exrow[n], isCos ? (float)cv : (float)sv, s);
                        }
                    }
                }
                float im = hsum16(s, 0);
                float re = hsum16(s, 16);
                if (lane == src) vout[j] = make_float2(re, -im);
            }
        }
        // gold nyq from gold taps (overrides the fast value)
        {
            float s = 0.0f;
            if (lane < 16) {
#pragma unroll 1
                for (int i = 0; i < 8; ++i) {
                    int base = 64 * i + lane;
                    s = fmarn(exrow[base +  0], s256f[base +  0], s);
                    s = fmarn(exrow[base + 16], s256f[base + 16], s);
                    s = fmarn(exrow[base + 32], s256f[base + 32], s);
                    s = fmarn(exrow[base + 48], s256f[base + 48], s);
                }
            }
            *nyq_out = -hsum16(s, 0);
        }
    }
    WAVE_SYNC();
}

// ---------------------------------------------------------------------------
__global__ __launch_bounds__(256) void dstft_fft_kernel(
    const float* __restrict__ x,
    const float* __restrict__ p_stride,
    const float* __restrict__ p_winlen,
    const float* __restrict__ p_winpow,
    const float* __restrict__ s256g,
    float2* __restrict__ scr, size_t scr_cap)
{
    __shared__ float ex[4][NF];
    __shared__ float s256f[NF];

    const int tid  = threadIdx.x;
    const int wv   = tid >> 6;
    const int lane = tid & 63;

    {
        s256f[tid]       = s256g[tid];
        s256f[tid + 256] = s256g[tid + 256];
    }
    __syncthreads();   // cross-wave: s256f shared by all waves

    float strd = p_stride[0];
    float wl   = fminf(fmaxf(p_winlen[0], (float)(512.0 / 20.0)), 512.0f);
    float wpow = p_winpow[0];

    const int t = blockIdx.x * 4 + wv;
    const int b = blockIdx.y;
    const bool active = (t < TT);

    float2 v[8];
    float nyq;
    dstft_frame_compute(x, strd, wl, wpow, v, ex[wv], s256f,
                        lane, t, b, active, &nyq);

    if (active) {
        size_t basez = ((size_t)b * TT + t) * NF;
        int k1 = bitrev6(lane);
#pragma unroll
        for (int j = 0; j < 8; ++j) {
            float2 vv = v[j];
            if (j == 0 && lane == 0) vv.y = neg_zero(); // gold: -(+0.0) = -0.0
            if (j == 0 && lane == 1) vv.y = nyq;        // gold npyv Nyquist
            size_t f = (size_t)(j + 8 * k1);
            if (basez + f < scr_cap) scr[basez + f] = vv;
        }
    }
}

// ---------------------------------------------------------------------------
__global__ __launch_bounds__(256) void dstft_epilogue(
    const float2* __restrict__ scr, size_t scr_cap,
    float* __restrict__ out, size_t oe, int layoutB)
{
    __shared__ float2 tile[32][33];
    const int tx = threadIdx.x;          // 0..31
    const int ty = threadIdx.y;          // 0..7
    const int t0 = blockIdx.x * 32;
    const int f0 = blockIdx.y * 32;
    const int b  = blockIdx.z;

#pragma unroll
    for (int i = 0; i < 4; ++i) {
        int tl = ty + 8 * i;
        int t  = t0 + tl;
        float2 v = make_float2(0.0f, 0.0f);
        size_t si = ((size_t)b * TT + t) * NF + (f0 + tx);
        if (t < TT && si < scr_cap) v = scr[si];
        tile[tl][tx] = v;
    }
    __syncthreads();

    const size_t off_stft  = SPEC_N;
    const size_t off_real  = layoutB ? (SPEC_N + BNT) : (SPEC_N + 2 * BNT);
    const size_t off_imag  = off_real + BNT;
    const size_t off_phase = off_imag + BNT;

#pragma unroll
    for (int i = 0; i < 4; ++i) {
        int fl = ty + 8 * i;
        int f  = f0 + fl;
        int t  = t0 + tx;
        if (t >= TT) continue;
        float2 v = tile[tx][fl];
        size_t o = ((size_t)b * NF + f) * TT + t;
        if (off_real + o < oe) out[off_real + o] = v.x;
        if (off_imag + o < oe) out[off_imag + o] = v.y;
        if (layoutB) {
            if (off_stft + o < oe) out[off_stft + o] = v.x;
        } else {
            size_t os = off_stft + 2 * o;
            if (os + 1 < oe) *reinterpret_cast<float2*>(out + os) = v;
        }
        if (f < FF) {
            size_t o2 = ((size_t)b * FF + f) * TT + t;
            if (o2 < oe) out[o2] = sqrtf(v.x * v.x + v.y * v.y) + 1.1920929e-7f;
            if (off_phase + o2 < oe) out[off_phase + o2] = atan2f(v.y, v.x);
        }
    }
}

// ---------------------------------------------------------------------------
// Fallback (ws too small): fused compute + direct writes.
__global__ __launch_bounds__(256) void dstft_fused(
    const float* __restrict__ x,
    const float* __restrict__ p_stride,
    const float* __restrict__ p_winlen,
    const float* __restrict__ p_winpow,
    float* __restrict__ out, size_t oe, int layoutB)
{
    __shared__ float ex[4][NF];
    __shared__ float s256f[NF];

    const int tid  = threadIdx.x;
    const int wv   = tid >> 6;
    const int lane = tid & 63;

    for (int k = tid; k < NF; k += 256)
        s256f[k] = (float)sin((double)theta32(256 * k));
    __syncthreads();

    float strd = p_stride[0];
    float wl   = fminf(fmaxf(p_winlen[0], (float)(512.0 / 20.0)), 512.0f);
    float wpow = p_winpow[0];

    const int t = blockIdx.x * 4 + wv;
    const int b = blockIdx.y;
    const bool active = (t < TT);

    float2 v[8];
    float nyq;
    dstft_frame_compute(x, strd, wl, wpow, v, ex[wv], s256f,
                        lane, t, b, active, &nyq);

    if (active) {
        const size_t off_stft  = SPEC_N;
        const size_t off_real  = layoutB ? (SPEC_N + BNT) : (SPEC_N + 2 * BNT);
        const size_t off_imag  = off_real + BNT;
        const size_t off_phase = off_imag + BNT;
        int k1 = bitrev6(lane);
#pragma unroll
        for (int j = 0; j < 8; ++j) {
            float2 vv = v[j];
            if (j == 0 && lane == 0) vv.y = neg_zero();
            if (j == 0 && lane == 1) vv.y = nyq;
            int f = j + 8 * k1;
            size_t o = ((size_t)b * NF + f) * TT + t;
            if (off_real + o < oe) out[off_real + o] = vv.x;
            if (off_imag + o < oe) out[off_imag + o] = vv.y;
            if (layoutB) {
                if (off_stft + o < oe) out[off_stft + o] = vv.x;
            } else {
                size_t os = off_stft + 2 * o;
                if (os + 1 < oe) { out[os] = vv.x; out[os + 1] = vv.y; }
            }
            if (f < FF) {
                size_t o2 = ((size_t)b * FF + f) * TT + t;
                if (o2 < oe) out[o2] = sqrtf(vv.x * vv.x + vv.y * vv.y) + 1.1920929e-7f;
                if (off_phase + o2 < oe) out[off_phase + o2] = atan2f(vv.y, vv.x);
            }
        }
    }
}

// ---------------------------------------------------------------------------
extern "C" void kernel_launch(void* const* d_in, const int* in_sizes, int n_in,
                              void* d_out, int out_size, void* d_ws, size_t ws_size,
                              hipStream_t stream)
{
    const float* x  = (const float*)d_in[0];
    const float* ps = (const float*)d_in[1];
    const float* pw = (const float*)d_in[2];
    const float* pp = (const float*)d_in[3];
    float* out = (float*)d_out;

    const size_t totalA = 2 * SPEC_N + 4 * BNT;   // 40,961,256
    int layoutB = ((size_t)out_size == totalA) ? 0 : 1;   // confirmed: B

    const size_t oe = (size_t)out_size;
    const size_t scrBytes = BNT * sizeof(float2);          // 65.5 MB
    const size_t needWs   = scrBytes + NF * sizeof(float); // + sin table
    const bool use_ws = (d_ws != nullptr) && (ws_size >= needWs);

    if (use_ws) {
        float2* scr   = (float2*)d_ws;
        float*  s256g = (float*)((char*)d_ws + scrBytes);
        dstft_sin256<<<1, NF, 0, stream>>>(s256g);
        dstft_fft_kernel<<<dim3((TT + 3) / 4, BB), 256, 0, stream>>>(
            x, ps, pw, pp, s256g, scr, BNT);
        dstft_epilogue<<<dim3((TT + 31) / 32, NF / 32, BB), dim3(32, 8), 0, stream>>>(
            scr, BNT, out, oe, layoutB);
    } else {
        dstft_fused<<<dim3((TT + 3) / 4, BB), 256, 0, stream>>>(
            x, ps, pw, pp, out, oe, layoutB);
    }
}